// Round 1
// baseline (75.630 us; speedup 1.0000x reference)
//
#include <hip/hip_runtime.h>

#define NQ 4
#define DIM 16
#define NL 3
#define INV_4PI 0.07957747154594767f  // rev = theta/(4*pi) -> sin(2*pi*rev) = sin(theta/2)

// Packed dual-FP32: lane processes TWO batch elements (A=.x, B=.y).
// gfx950 selects v_pk_fma_f32 / v_pk_mul_f32 / v_pk_add_f32 from <2 x float> IR.
typedef float v2f __attribute__((ext_vector_type(2)));

// ---- ring permutation, generated exactly as the reference composes it ----
__host__ __device__ constexpr int cnot_perm(int idx, int c, int t) {
    return idx ^ (((idx >> (3 - c)) & 1) << (3 - t));
}
__host__ __device__ constexpr int ring_idx(int j) {
    int v = j;
    for (int c = 3; c >= 0; --c) v = cnot_perm(v, c, (c + 1) & 3);
    return v;
}
// Slot map after l ring-perms have been *folded away*: sigma_l(i) = ring_idx^l(i).
// Instead of physically permuting st[] (which created a 32-VGPR temp array with
// all of st still live, 3x per kernel), gates at layer l simply address the
// permuted register slots at compile time. Zero instructions, zero pressure spike.
__host__ __device__ constexpr int rp_pow(int i, int l) {
    int v = i;
    for (int t = 0; t < l; ++t) v = ring_idx(v);
    return v;
}

template <int Q, int LYR>
__device__ __forceinline__ void apply_ry(v2f st[16], float c, float s) {
    constexpr int stride = 1 << (3 - Q);  // qubit q <-> index bit (3-q)
    const v2f cc = {c, c}, ss = {s, s};
    #pragma unroll
    for (int i = 0; i < 16; ++i) {
        if ((i & stride) == 0) {
            const int a = rp_pow(i, LYR);           // compile-time slot of logical i
            const int b = rp_pow(i | stride, LYR);  // compile-time slot of logical i|stride
            const v2f s0 = st[a], s1 = st[b];
            st[a] = __builtin_elementwise_fma(cc, s0, -(ss * s1));  // pk_fma with neg modifier
            st[b] = __builtin_elementwise_fma(cc, s1, ss * s0);
        }
    }
}

// launch_bounds(256, 8): 8 waves/EU min -> forces VGPR <= 64 -> full 32 waves/CU,
// entire 8192-wave grid resident in a single occupancy pass.
__global__ void __launch_bounds__(256, 8)
qlayer_kernel(const float* __restrict__ x, const float* __restrict__ w,
              float* __restrict__ out, int B) {
    // ---- once-per-wave: all 24 weight sin/cos in ONE v_sin across lanes ----
    const int lane = threadIdx.x & 63;
    const int k = lane < 12 ? lane : (lane < 24 ? lane - 12 : 0);
    const float wk = w[k];
    const float rev = __builtin_fmaf(wk, INV_4PI, (lane >= 12) ? 0.25f : 0.0f);
    const int ti = __float_as_int(__builtin_amdgcn_sinf(rev));
    float cw[12], sw[12];  // uniform -> SGPRs
    #pragma unroll
    for (int kk = 0; kk < 12; ++kk) {
        sw[kk] = __int_as_float(__builtin_amdgcn_readlane(ti, kk));
        cw[kk] = __int_as_float(__builtin_amdgcn_readlane(ti, kk + 12));
    }

    const int half = B >> 1;
    const int t0i = blockIdx.x * blockDim.x + threadIdx.x;
    if (t0i >= half) return;
    const int bA = t0i;          // element A
    const int bB = t0i + half;   // element B  (both float4 accesses stay coalesced)

    // ---- input layer: product state, built packed {A,B} ----
    const float4 xA = ((const float4*)x)[bA];
    const float4 xB = ((const float4*)x)[bB];
    const float rA0 = xA.x * INV_4PI, rA1 = xA.y * INV_4PI, rA2 = xA.z * INV_4PI, rA3 = xA.w * INV_4PI;
    const float rB0 = xB.x * INV_4PI, rB1 = xB.y * INV_4PI, rB2 = xB.z * INV_4PI, rB3 = xB.w * INV_4PI;

    const v2f C0 = {__builtin_amdgcn_cosf(rA0), __builtin_amdgcn_cosf(rB0)};
    const v2f S0 = {__builtin_amdgcn_sinf(rA0), __builtin_amdgcn_sinf(rB0)};
    const v2f C1 = {__builtin_amdgcn_cosf(rA1), __builtin_amdgcn_cosf(rB1)};
    const v2f S1 = {__builtin_amdgcn_sinf(rA1), __builtin_amdgcn_sinf(rB1)};
    const v2f C2 = {__builtin_amdgcn_cosf(rA2), __builtin_amdgcn_cosf(rB2)};
    const v2f S2 = {__builtin_amdgcn_sinf(rA2), __builtin_amdgcn_sinf(rB2)};
    const v2f C3 = {__builtin_amdgcn_cosf(rA3), __builtin_amdgcn_cosf(rB3)};
    const v2f S3 = {__builtin_amdgcn_sinf(rA3), __builtin_amdgcn_sinf(rB3)};

    // qubit q <-> index bit (3-q); bit set => sin factor
    const v2f H[4] = {C0 * C1, C0 * S1, S0 * C1, S0 * S1};  // bits (b3,b2)
    const v2f L[4] = {C2 * C3, C2 * S3, S2 * C3, S2 * S3};  // bits (b1,b0)
    v2f st[16];
    #pragma unroll
    for (int i = 0; i < 16; ++i) st[i] = H[i >> 2] * L[i & 3];

    // ---- 3 layers of uniform-angle RYs; ring perms folded into slot maps ----
    apply_ry<0, 0>(st, cw[0],  sw[0]);
    apply_ry<1, 0>(st, cw[1],  sw[1]);
    apply_ry<2, 0>(st, cw[2],  sw[2]);
    apply_ry<3, 0>(st, cw[3],  sw[3]);

    apply_ry<0, 1>(st, cw[4],  sw[4]);
    apply_ry<1, 1>(st, cw[5],  sw[5]);
    apply_ry<2, 1>(st, cw[6],  sw[6]);
    apply_ry<3, 1>(st, cw[7],  sw[7]);

    apply_ry<0, 2>(st, cw[8],  sw[8]);
    apply_ry<1, 2>(st, cw[9],  sw[9]);
    apply_ry<2, 2>(st, cw[10], sw[10]);
    apply_ry<3, 2>(st, cw[11], sw[11]);

    // ---- probs (read through final slot map) + signed butterfly, all packed ----
    v2f p[16];
    #pragma unroll
    for (int i = 0; i < 16; ++i) {
        const int m = rp_pow(i, 3);
        p[i] = st[m] * st[m];
    }

    v2f a[8], o3 = {0.0f, 0.0f};
    #pragma unroll
    for (int kk = 0; kk < 8; ++kk) {
        a[kk] = p[2 * kk] + p[2 * kk + 1];
        o3 += p[2 * kk] - p[2 * kk + 1];
    }
    v2f e[4], o2 = {0.0f, 0.0f};
    #pragma unroll
    for (int m = 0; m < 4; ++m) {
        e[m] = a[2 * m] + a[2 * m + 1];
        o2 += a[2 * m] - a[2 * m + 1];
    }
    const v2f o1 = (e[0] - e[1]) + (e[2] - e[3]);
    const v2f o0 = (e[0] + e[1]) - (e[2] + e[3]);

    ((float4*)out)[bA] = make_float4(o0.x, o1.x, o2.x, o3.x);
    ((float4*)out)[bB] = make_float4(o0.y, o1.y, o2.y, o3.y);
}

extern "C" void kernel_launch(void* const* d_in, const int* in_sizes, int n_in,
                              void* d_out, int out_size, void* d_ws, size_t ws_size,
                              hipStream_t stream) {
    const float* x = (const float*)d_in[0];
    const float* w = (const float*)d_in[1];
    float* out = (float*)d_out;
    const int B = in_sizes[0] / 4;
    const int half = B >> 1;
    const int block = 256;
    const int grid = (half + block - 1) / block;
    qlayer_kernel<<<grid, block, 0, stream>>>(x, w, out, B);
}

// Round 2
// 75.202 us; speedup vs baseline: 1.0057x; 1.0057x over previous
//
#include <hip/hip_runtime.h>

#define NQ 4
#define DIM 16
#define NL 3
#define INV_4PI 0.07957747154594767f  // rev = theta/(4*pi) -> sin(2*pi*rev) = sin(theta/2)

// Packed dual-FP32: lane processes TWO batch elements (A=.x, B=.y).
// gfx950 selects v_pk_fma_f32 / v_pk_mul_f32 / v_pk_add_f32 from <2 x float> IR.
typedef float v2f __attribute__((ext_vector_type(2)));

// ---- ring permutation, generated exactly as the reference composes it ----
__host__ __device__ constexpr int cnot_perm(int idx, int c, int t) {
    return idx ^ (((idx >> (3 - c)) & 1) << (3 - t));
}
__host__ __device__ constexpr int ring_idx(int j) {
    int v = j;
    for (int c = 3; c >= 0; --c) v = cnot_perm(v, c, (c + 1) & 3);
    return v;
}
// Slot map after l ring-perms folded away: gates at layer l address slot
// rp_pow(i, l) at compile time; no physical permute ever happens.
// (Verified correct in R1: absmax unchanged vs physical-permute version.)
__host__ __device__ constexpr int rp_pow(int i, int l) {
    int v = i;
    for (int t = 0; t < l; ++t) v = ring_idx(v);
    return v;
}

template <int Q, int LYR>
__device__ __forceinline__ void apply_ry(v2f st[16], float c, float s) {
    constexpr int stride = 1 << (3 - Q);  // qubit q <-> index bit (3-q)
    const v2f cc = {c, c}, ss = {s, s};
    #pragma unroll
    for (int i = 0; i < 16; ++i) {
        if ((i & stride) == 0) {
            const int a = rp_pow(i, LYR);
            const int b = rp_pow(i | stride, LYR);
            const v2f s0 = st[a], s1 = st[b];
            st[a] = __builtin_elementwise_fma(cc, s0, -(ss * s1));  // pk_fma with neg modifier
            st[b] = __builtin_elementwise_fma(cc, s1, ss * s0);
        }
    }
}

// (256, 8): 8 waves/EU -> VGPR cap 64 -> 32 waves/CU, whole grid in one pass.
// R2 change: epilogue is now streamed (no p[16] array), peak liveness ~50 VGPRs,
// so the cap is met WITHOUT scratch spills (R1 plausibly spilled: st[16]+p[16]
// = 64 VGPRs live simultaneously under a 64-register budget).
__global__ void __launch_bounds__(256, 8)
qlayer_kernel(const float* __restrict__ x, const float* __restrict__ w,
              float* __restrict__ out, int B) {
    // ---- once-per-wave: all 24 weight sin/cos in ONE v_sin across lanes ----
    const int lane = threadIdx.x & 63;
    const int k = lane < 12 ? lane : (lane < 24 ? lane - 12 : 0);
    const float wk = w[k];
    const float rev = __builtin_fmaf(wk, INV_4PI, (lane >= 12) ? 0.25f : 0.0f);
    const int ti = __float_as_int(__builtin_amdgcn_sinf(rev));
    float cw[12], sw[12];  // uniform readlane results -> SGPRs
    #pragma unroll
    for (int kk = 0; kk < 12; ++kk) {
        sw[kk] = __int_as_float(__builtin_amdgcn_readlane(ti, kk));
        cw[kk] = __int_as_float(__builtin_amdgcn_readlane(ti, kk + 12));
    }

    const int half = B >> 1;
    const int t0i = blockIdx.x * blockDim.x + threadIdx.x;
    if (t0i >= half) return;
    const int bA = t0i;          // element A
    const int bB = t0i + half;   // element B  (both float4 accesses stay coalesced)

    // ---- input layer: product state, built packed {A,B} ----
    const float4 xA = ((const float4*)x)[bA];
    const float4 xB = ((const float4*)x)[bB];
    const float rA0 = xA.x * INV_4PI, rA1 = xA.y * INV_4PI, rA2 = xA.z * INV_4PI, rA3 = xA.w * INV_4PI;
    const float rB0 = xB.x * INV_4PI, rB1 = xB.y * INV_4PI, rB2 = xB.z * INV_4PI, rB3 = xB.w * INV_4PI;

    const v2f C0 = {__builtin_amdgcn_cosf(rA0), __builtin_amdgcn_cosf(rB0)};
    const v2f S0 = {__builtin_amdgcn_sinf(rA0), __builtin_amdgcn_sinf(rB0)};
    const v2f C1 = {__builtin_amdgcn_cosf(rA1), __builtin_amdgcn_cosf(rB1)};
    const v2f S1 = {__builtin_amdgcn_sinf(rA1), __builtin_amdgcn_sinf(rB1)};
    const v2f C2 = {__builtin_amdgcn_cosf(rA2), __builtin_amdgcn_cosf(rB2)};
    const v2f S2 = {__builtin_amdgcn_sinf(rA2), __builtin_amdgcn_sinf(rB2)};
    const v2f C3 = {__builtin_amdgcn_cosf(rA3), __builtin_amdgcn_cosf(rB3)};
    const v2f S3 = {__builtin_amdgcn_sinf(rA3), __builtin_amdgcn_sinf(rB3)};

    // qubit q <-> index bit (3-q); bit set => sin factor
    const v2f H[4] = {C0 * C1, C0 * S1, S0 * C1, S0 * S1};  // bits (b3,b2)
    const v2f L[4] = {C2 * C3, C2 * S3, S2 * C3, S2 * S3};  // bits (b1,b0)
    v2f st[16];
    #pragma unroll
    for (int i = 0; i < 16; ++i) st[i] = H[i >> 2] * L[i & 3];

    // ---- 3 layers of uniform-angle RYs; ring perms folded into slot maps ----
    apply_ry<0, 0>(st, cw[0],  sw[0]);
    apply_ry<1, 0>(st, cw[1],  sw[1]);
    apply_ry<2, 0>(st, cw[2],  sw[2]);
    apply_ry<3, 0>(st, cw[3],  sw[3]);

    apply_ry<0, 1>(st, cw[4],  sw[4]);
    apply_ry<1, 1>(st, cw[5],  sw[5]);
    apply_ry<2, 1>(st, cw[6],  sw[6]);
    apply_ry<3, 1>(st, cw[7],  sw[7]);

    apply_ry<0, 2>(st, cw[8],  sw[8]);
    apply_ry<1, 2>(st, cw[9],  sw[9]);
    apply_ry<2, 2>(st, cw[10], sw[10]);
    apply_ry<3, 2>(st, cw[11], sw[11]);

    // ---- STREAMED epilogue: probs consumed pairwise, st dies progressively.
    // Never materializes p[16] (which made st+p = 64 VGPRs live at once).
    v2f a[8], o3 = {0.0f, 0.0f};
    #pragma unroll
    for (int kk = 0; kk < 8; ++kk) {
        const int m0 = rp_pow(2 * kk, 3);      // final slot map folded in
        const int m1 = rp_pow(2 * kk + 1, 3);
        const v2f p0 = st[m0] * st[m0];
        const v2f p1 = st[m1] * st[m1];
        a[kk] = p0 + p1;
        o3 += p0 - p1;
    }
    v2f e[4], o2 = {0.0f, 0.0f};
    #pragma unroll
    for (int m = 0; m < 4; ++m) {
        e[m] = a[2 * m] + a[2 * m + 1];
        o2 += a[2 * m] - a[2 * m + 1];
    }
    const v2f o1 = (e[0] - e[1]) + (e[2] - e[3]);
    const v2f o0 = (e[0] + e[1]) - (e[2] + e[3]);

    ((float4*)out)[bA] = make_float4(o0.x, o1.x, o2.x, o3.x);
    ((float4*)out)[bB] = make_float4(o0.y, o1.y, o2.y, o3.y);
}

extern "C" void kernel_launch(void* const* d_in, const int* in_sizes, int n_in,
                              void* d_out, int out_size, void* d_ws, size_t ws_size,
                              hipStream_t stream) {
    const float* x = (const float*)d_in[0];
    const float* w = (const float*)d_in[1];
    float* out = (float*)d_out;
    const int B = in_sizes[0] / 4;
    const int half = B >> 1;
    const int block = 256;
    const int grid = (half + block - 1) / block;
    qlayer_kernel<<<grid, block, 0, stream>>>(x, w, out, B);
}